// Round 2
// baseline (738.287 us; speedup 1.0000x reference)
//
#include <hip/hip_runtime.h>
#include <hip/hip_bf16.h>

#define N_NODES   100000
#define N_EDGES   3200000
#define N_FEAT    128
#define HIDDEN    16
#define N_CLASSES 10
#define N_GRAPHS  64
#define NCHUNK    391          // ceil(100000/256)

// Workspace layout (4-byte units):
//   deg_i    [0,       100000)  int   zeroed via memset
//   row_start[100000,  200000)  int
//   fill_pos [200000,  300000)  int
//   partials [300000,  300391)  int
//   scan_off [300400,  300791)  int
//   csr_src  [300800, 3500800)  int
//   dinv     [3500800, 3600800) f32
//   h1       [3600800, 5200800) f32  stride 16
//   h2       [5200800, 6800800) f32  stride 16 (cols 10..15 zero-padded)
//   out_node = h1 (reused)            stride 16
// total 27.2 MB

__global__ __launch_bounds__(256) void k_hist(const int* __restrict__ dst,
                                              int* __restrict__ deg) {
    int e = blockIdx.x * 256 + threadIdx.x;
    atomicAdd(&deg[dst[e]], 1);
}

__global__ __launch_bounds__(256) void k_scan1(const int* __restrict__ deg,
                                               float* __restrict__ dinv,
                                               int* __restrict__ partials) {
    __shared__ int red[256];
    int tid = threadIdx.x;
    int i = blockIdx.x * 256 + tid;
    int d = 0;
    if (i < N_NODES) {
        d = deg[i];
        dinv[i] = rsqrtf((float)d + 1.0f);
    }
    red[tid] = d;
    __syncthreads();
    for (int s = 128; s > 0; s >>= 1) {
        if (tid < s) red[tid] += red[tid + s];
        __syncthreads();
    }
    if (tid == 0) partials[blockIdx.x] = red[0];
}

__global__ __launch_bounds__(512) void k_scan2(const int* __restrict__ partials,
                                               int* __restrict__ scan_off) {
    __shared__ int s[512];
    int tid = threadIdx.x;
    int v = (tid < NCHUNK) ? partials[tid] : 0;
    s[tid] = v;
    __syncthreads();
    for (int off = 1; off < 512; off <<= 1) {
        int t = (tid >= off) ? s[tid - off] : 0;
        __syncthreads();
        s[tid] += t;
        __syncthreads();
    }
    if (tid < NCHUNK) scan_off[tid] = s[tid] - v;   // exclusive
}

__global__ __launch_bounds__(256) void k_scan3(const int* __restrict__ deg,
                                               const int* __restrict__ scan_off,
                                               int* __restrict__ row_start,
                                               int* __restrict__ fill_pos) {
    __shared__ int s[256];
    int tid = threadIdx.x;
    int i = blockIdx.x * 256 + tid;
    int d = (i < N_NODES) ? deg[i] : 0;
    s[tid] = d;
    __syncthreads();
    for (int off = 1; off < 256; off <<= 1) {
        int t = (tid >= off) ? s[tid - off] : 0;
        __syncthreads();
        s[tid] += t;
        __syncthreads();
    }
    if (i < N_NODES) {
        int row = scan_off[blockIdx.x] + s[tid] - d;   // exclusive
        row_start[i] = row;
        fill_pos[i]  = row;
    }
}

__global__ __launch_bounds__(256) void k_fill(const int* __restrict__ src,
                                              const int* __restrict__ dst,
                                              int* __restrict__ fill_pos,
                                              int* __restrict__ csr_src) {
    int e = blockIdx.x * 256 + threadIdx.x;
    int d = dst[e];
    int pos = atomicAdd(&fill_pos[d], 1);
    csr_src[pos] = src[e];
}

// 16 nodes per block; W1 and the x-tile staged in LDS.
__global__ __launch_bounds__(256) void k_gemm1(const float* __restrict__ x,
                                               const float* __restrict__ W1,
                                               float* __restrict__ h1) {
    __shared__ float w[N_FEAT * HIDDEN];   // 8 KB
    __shared__ float xs[16 * N_FEAT];      // 8 KB
    int tid  = threadIdx.x;
    int base = blockIdx.x * 16;
#pragma unroll
    for (int k = 0; k < 8; ++k) w[k * 256 + tid] = W1[k * 256 + tid];
#pragma unroll
    for (int k = 0; k < 8; ++k)
        xs[k * 256 + tid] = x[base * N_FEAT + k * 256 + tid];
    __syncthreads();
    int n = tid >> 4, c = tid & 15;
    const float* xr = &xs[n * N_FEAT];
    float acc = 0.f;
#pragma unroll 8
    for (int k = 0; k < N_FEAT; ++k) acc += xr[k] * w[k * HIDDEN + c];
    h1[(base + n) * HIDDEN + c] = acc;
}

// Gather-aggregate layer 1 + fused self-loop + b1 + ReLU + @W2 -> h2.
// 16 lanes per node (one per hidden channel); LDS transpose for the W2 matmul.
__global__ __launch_bounds__(256) void k_agg1(const int* __restrict__ row_start,
                                              const int* __restrict__ deg,
                                              const int* __restrict__ csr_src,
                                              const float* __restrict__ dinv,
                                              const float* __restrict__ h1,
                                              const float* __restrict__ b1,
                                              const float* __restrict__ W2,
                                              float* __restrict__ h2) {
    __shared__ float w2s[HIDDEN * N_CLASSES];
    __shared__ float b1s[HIDDEN];
    __shared__ float rs[16][17];
    int tid = threadIdx.x;
    if (tid < HIDDEN * N_CLASSES) w2s[tid] = W2[tid];
    if (tid < HIDDEN) b1s[tid] = b1[tid];
    __syncthreads();

    int n    = tid >> 4;
    int c    = tid & 15;
    int node = blockIdx.x * 16 + n;
    float r  = 0.f;
    if (node < N_NODES) {
        float dv  = dinv[node];
        int   st  = row_start[node];
        int   cnt = deg[node];
        float acc = 0.f;
        for (int j = 0; j < cnt; ++j) {
            int s = csr_src[st + j];
            acc += dinv[s] * h1[s * HIDDEN + c];
        }
        r = fmaxf(dv * acc + h1[node * HIDDEN + c] * dv * dv + b1s[c], 0.f);
    }
    rs[n][c] = r;
    __syncthreads();

    if (node < N_NODES) {
        float o = 0.f;
        if (c < N_CLASSES) {
#pragma unroll
            for (int k = 0; k < HIDDEN; ++k) o += rs[n][k] * w2s[k * N_CLASSES + c];
        }
        h2[node * HIDDEN + c] = o;   // cols 10..15 = 0 (zero padding)
    }
}

// Gather-aggregate layer 2 + self-loop -> out_node (stride 16, b2 at pool).
__global__ __launch_bounds__(256) void k_agg2(const int* __restrict__ row_start,
                                              const int* __restrict__ deg,
                                              const int* __restrict__ csr_src,
                                              const float* __restrict__ dinv,
                                              const float* __restrict__ h2,
                                              float* __restrict__ out_node) {
    int tid  = threadIdx.x;
    int node = blockIdx.x * 16 + (tid >> 4);
    int c    = tid & 15;
    if (node >= N_NODES) return;
    float dv  = dinv[node];
    int   st  = row_start[node];
    int   cnt = deg[node];
    float acc = 0.f;
    for (int j = 0; j < cnt; ++j) {
        int s = csr_src[st + j];
        acc += dinv[s] * h2[s * HIDDEN + c];
    }
    out_node[node * HIDDEN + c] = dv * acc + h2[node * HIDDEN + c] * dv * dv;
}

// one block per graph; batch is sorted -> binary search the node range,
// block-reduce sums, then log_softmax straight to d_out.
__global__ __launch_bounds__(256) void k_pool(const float* __restrict__ out_node,
                                              const float* __restrict__ b2,
                                              const int* __restrict__ batch,
                                              float* __restrict__ out) {
    __shared__ float red[N_CLASSES][256];
    int g = blockIdx.x, tid = threadIdx.x;
    int lo = 0, hi = N_NODES;
    while (lo < hi) { int m = (lo + hi) >> 1; if (batch[m] < g) lo = m + 1; else hi = m; }
    int start = lo;
    lo = 0; hi = N_NODES;
    while (lo < hi) { int m = (lo + hi) >> 1; if (batch[m] < g + 1) lo = m + 1; else hi = m; }
    int end = lo;

    float sum[N_CLASSES];
#pragma unroll
    for (int j = 0; j < N_CLASSES; ++j) sum[j] = 0.f;
    for (int i = start + tid; i < end; i += 256) {
#pragma unroll
        for (int j = 0; j < N_CLASSES; ++j) sum[j] += out_node[i * HIDDEN + j];
    }
#pragma unroll
    for (int j = 0; j < N_CLASSES; ++j) red[j][tid] = sum[j];
    __syncthreads();
    for (int s = 128; s > 0; s >>= 1) {
        if (tid < s) {
#pragma unroll
            for (int j = 0; j < N_CLASSES; ++j) red[j][tid] += red[j][tid + s];
        }
        __syncthreads();
    }
    if (tid == 0) {
        int cnt = end - start;
        float v[N_CLASSES];
        if (cnt > 0) {
            float inv = 1.f / (float)cnt;
#pragma unroll
            for (int j = 0; j < N_CLASSES; ++j) v[j] = red[j][0] * inv + b2[j];
        } else {
#pragma unroll
            for (int j = 0; j < N_CLASSES; ++j) v[j] = 0.f;
        }
        float m = v[0];
#pragma unroll
        for (int j = 1; j < N_CLASSES; ++j) m = fmaxf(m, v[j]);
        float l = 0.f;
#pragma unroll
        for (int j = 0; j < N_CLASSES; ++j) l += expf(v[j] - m);
        l = logf(l);
#pragma unroll
        for (int j = 0; j < N_CLASSES; ++j) out[g * N_CLASSES + j] = v[j] - m - l;
    }
}

extern "C" void kernel_launch(void* const* d_in, const int* in_sizes, int n_in,
                              void* d_out, int out_size, void* d_ws, size_t ws_size,
                              hipStream_t stream) {
    const float* x     = (const float*)d_in[0];
    const int*   edge  = (const int*)d_in[1];   // [2, E] (int64 narrowed to int32 by harness)
    const int*   batch = (const int*)d_in[2];
    const float* W1    = (const float*)d_in[3];
    const float* b1    = (const float*)d_in[4];
    const float* W2    = (const float*)d_in[5];
    const float* b2    = (const float*)d_in[6];
    float* out = (float*)d_out;

    int*   iw       = (int*)d_ws;
    int*   deg_i    = iw;
    int*   row_start= iw + 100000;
    int*   fill_pos = iw + 200000;
    int*   partials = iw + 300000;
    int*   scan_off = iw + 300400;
    int*   csr_src  = iw + 300800;
    float* fw       = (float*)d_ws;
    float* dinv     = fw + 3500800;
    float* h1       = fw + 3600800;
    float* h2       = fw + 5200800;
    float* out_node = h1;            // h1 dead after k_agg1

    const int* srcp = edge;
    const int* dstp = edge + N_EDGES;

    hipMemsetAsync(deg_i, 0, N_NODES * sizeof(int), stream);

    k_hist <<<N_EDGES / 256, 256, 0, stream>>>(dstp, deg_i);
    k_scan1<<<NCHUNK,        256, 0, stream>>>(deg_i, dinv, partials);
    k_scan2<<<1,             512, 0, stream>>>(partials, scan_off);
    k_scan3<<<NCHUNK,        256, 0, stream>>>(deg_i, scan_off, row_start, fill_pos);
    k_fill <<<N_EDGES / 256, 256, 0, stream>>>(srcp, dstp, fill_pos, csr_src);
    k_gemm1<<<N_NODES / 16,  256, 0, stream>>>(x, W1, h1);
    k_agg1 <<<(N_NODES + 15) / 16, 256, 0, stream>>>(row_start, deg_i, csr_src,
                                                     dinv, h1, b1, W2, h2);
    k_agg2 <<<(N_NODES + 15) / 16, 256, 0, stream>>>(row_start, deg_i, csr_src,
                                                     dinv, h2, out_node);
    k_pool <<<N_GRAPHS,      256, 0, stream>>>(out_node, b2, batch, out);
}